// Round 7
// baseline (103.058 us; speedup 1.0000x reference)
//
#include <hip/hip_runtime.h>
#include <hip/hip_fp16.h>

typedef _Float16 half8 __attribute__((ext_vector_type(8)));
typedef float f32x4 __attribute__((ext_vector_type(4)));

#define B_   8192
#define DIN  2048
#define C_   1000
#define CP   1024
#define NP2  512   // u,v interleaved rows

// ---- workspace layout (bytes) ----
static const size_t OFF_XH  = 0;                                   // xh  [8192][2048] f16
static const size_t OFF_WH  = OFF_XH  + (size_t)B_ * DIN * 2;      // wh  [1024][2048] f16 (rows>=1000 zero)
static const size_t OFF_UVH = OFF_WH  + (size_t)CP * DIN * 2;      // uvh [512][1024]  f16
static const size_t OFF_PH  = OFF_UVH + (size_t)NP2 * CP * 2;      // predsh [8192][1024] f16
static const size_t OFF_SC  = OFF_PH  + (size_t)B_ * CP * 2;       // scores [8192] f32
static const size_t OFF_RS  = OFF_SC  + (size_t)B_ * 4;            // rowsum [8192] f32
static const size_t WS_NEED = OFF_RS  + (size_t)B_ * 4;

#define FENCE asm volatile("" ::: "memory")
#define BARRIER do { FENCE; __builtin_amdgcn_s_barrier(); FENCE; } while (0)
#define VMCNT(n) asm volatile("s_waitcnt vmcnt(" #n ")" ::: "memory")
#define PRIO1 __builtin_amdgcn_s_setprio(1)
#define PRIO0 __builtin_amdgcn_s_setprio(0)

__device__ __forceinline__ void gload16(const void* g, void* l) {
  __builtin_amdgcn_global_load_lds(
      (const __attribute__((address_space(1))) void*)g,
      (__attribute__((address_space(3))) void*)l, 16, 0, 0);
}

// ---------------- prep: f32 -> f16 conversions + zeroing (r5-validated) ----------------
__global__ __launch_bounds__(256) void prep_kernel(
    const float* __restrict__ x, const float* __restrict__ Wm,
    const float* __restrict__ u, const float* __restrict__ v,
    _Float16* __restrict__ xh, _Float16* __restrict__ wh,
    _Float16* __restrict__ uvh, float* __restrict__ scores,
    float* __restrict__ rowsum)
{
  const long NX  = (long)B_ * DIN / 8;
  const long NW  = (long)CP * DIN / 8;
  const long NUV = (long)NP2 * CP / 8;
  const long NZ  = 2 * (long)B_ / 8;
  const long T   = NX + NW + NUV + NZ;
  for (long idx = (long)blockIdx.x * blockDim.x + threadIdx.x; idx < T;
       idx += (long)gridDim.x * blockDim.x) {
    if (idx < NX) {
      long e = idx * 8;
      float4 p0 = *(const float4*)(x + e);
      float4 p1 = *(const float4*)(x + e + 4);
      half8 h;
      h[0] = (_Float16)p0.x; h[1] = (_Float16)p0.y; h[2] = (_Float16)p0.z; h[3] = (_Float16)p0.w;
      h[4] = (_Float16)p1.x; h[5] = (_Float16)p1.y; h[6] = (_Float16)p1.z; h[7] = (_Float16)p1.w;
      *(half8*)(xh + e) = h;
    } else if (idx < NX + NW) {
      long e = (idx - NX) * 8;
      int row = (int)(e >> 11);
      half8 h;
      if (row < C_) {
        float4 p0 = *(const float4*)(Wm + e);
        float4 p1 = *(const float4*)(Wm + e + 4);
        h[0] = (_Float16)p0.x; h[1] = (_Float16)p0.y; h[2] = (_Float16)p0.z; h[3] = (_Float16)p0.w;
        h[4] = (_Float16)p1.x; h[5] = (_Float16)p1.y; h[6] = (_Float16)p1.z; h[7] = (_Float16)p1.w;
      } else {
        h = (half8)(_Float16)0.f;
      }
      *(half8*)(wh + e) = h;
    } else if (idx < NX + NW + NUV) {
      long e = (idx - NX - NW) * 8;
      int j = (int)(e >> 10);
      int k = (int)(e & 1023);
      const float* src = (j & 1) ? v : u;
      int p = j >> 1;
      half8 h;
      #pragma unroll
      for (int t = 0; t < 8; ++t) {
        int kk = k + t;
        h[t] = (kk < C_) ? (_Float16)src[(size_t)p * C_ + kk] : (_Float16)0.f;
      }
      *(half8*)(uvh + e) = h;
    } else {
      long e = (idx - NX - NW - NUV) * 8;
      float4 z = {0.f, 0.f, 0.f, 0.f};
      if (e < B_) {
        *(float4*)(scores + e) = z; *(float4*)(scores + e + 4) = z;
      } else {
        long r = e - B_;
        *(float4*)(rowsum + r) = z; *(float4*)(rowsum + r + 4) = z;
      }
    }
  }
}

// ---------------- main GEMM: preds = xh @ wh^T + bm ----------------
// 256x128 tile, BK=64, 256 threads = 4 waves (2M x 2N), wave tile 128x64
// (LDS-read per CU per K-tile: 4x(128+64)x64x2B = 96KB < MFMA 1242cyc floor
//  -> MFMA-bound, vs r5's 8x64x64 = 128KB LDS-read-bound).
// 3-buffer LDS. 4 phases/tile: {quad ds_reads + 3 gload_lds -> barrier ->
// 16 MFMA}. Quadrant reads 1-2 phases ahead of use: P0 rd AH(t); P1 rd BH(t);
// P2 rd BL(t+1); P3 rd AL(t+1). Single derived wait per tile: vmcnt(6) at P1
// (retires t+1's 12 loads; t+2's 6 newest stay in flight) BEFORE the barrier
// that precedes any read of t+1 data.
__global__ __launch_bounds__(256, 1) void gemm1_kernel(
    const _Float16* __restrict__ xh, const _Float16* __restrict__ wh,
    const float* __restrict__ bmv, float* __restrict__ preds,
    _Float16* __restrict__ predsh, float* __restrict__ rowsum)
{
  // A bufs (256x64 f16 = 32KB) at c*32768 ; B bufs (128x64 = 16KB) at 98304 + c*16384
  __shared__ _Float16 lds[(3 * 32768 + 3 * 16384) / 2];   // 144 KB
  char* const LB = (char*)lds;
  const int tid  = threadIdx.x;
  const int lane = tid & 63;
  const int w    = tid >> 6;       // 0..3
  const int wm   = w >> 1;         // 0..1 (M half: 128 rows)
  const int wn   = w & 1;          // 0..1 (N half: 64 cols)
  const int bm0  = blockIdx.x * 256;
  const int bn0  = blockIdx.y * 128;

  f32x4 acc[8][4] = {};

  // staging sources: slot = k*256+tid -> row = k*32 + (tid>>3); swizzle is
  // k-independent since k*32 % 8 == 0. Pre-swizzled source, linear LDS dest.
  const int trow = tid >> 3;                       // 0..31
  const int swzc = (((tid & 7) << 4) ^ ((trow & 7) << 4)) >> 1;  // f16 units
  const _Float16* pA = xh + (size_t)(bm0 + trow) * DIN + swzc;
  const _Float16* pB = wh + (size_t)(bn0 + trow) * DIN + swzc;

  // ds_read fragment byte offsets (within one A / B buffer)
  int aoff[8][2], boff[4][2];
  #pragma unroll
  for (int m = 0; m < 8; ++m)
    #pragma unroll
    for (int ks = 0; ks < 2; ++ks) {
      int ra = wm * 128 + m * 16 + (lane & 15);
      int kb = ks * 64 + (lane >> 4) * 16;
      aoff[m][ks] = ra * 128 + (kb ^ ((ra & 7) << 4));
    }
  #pragma unroll
  for (int n = 0; n < 4; ++n)
    #pragma unroll
    for (int ks = 0; ks < 2; ++ks) {
      int rb = wn * 64 + n * 16 + (lane & 15);
      int kb = ks * 64 + (lane >> 4) * 16;
      boff[n][ks] = rb * 128 + (kb ^ ((rb & 7) << 4));
    }

  half8 A[8][2], Bf[4][2];   // fragment registers (96 VGPR) + acc 128

  auto stA = [&](int c, int k) {
    gload16(pA + (size_t)k * 32 * DIN, LB + c * 32768 + k * 4096 + w * 1024);
  };
  auto stB = [&](int c, int k) {
    gload16(pB + (size_t)k * 32 * DIN, LB + 98304 + c * 16384 + k * 4096 + w * 1024);
  };
  auto advance = [&]() { pA += 64; pB += 64; };

  auto rdAL = [&](int c) {   // m 0..3
    const char* b = LB + c * 32768;
    #pragma unroll
    for (int m = 0; m < 4; ++m)
      #pragma unroll
      for (int ks = 0; ks < 2; ++ks)
        A[m][ks] = *(const half8*)(b + aoff[m][ks]);
  };
  auto rdAH = [&](int c) {   // m 4..7
    const char* b = LB + c * 32768;
    #pragma unroll
    for (int m = 4; m < 8; ++m)
      #pragma unroll
      for (int ks = 0; ks < 2; ++ks)
        A[m][ks] = *(const half8*)(b + aoff[m][ks]);
  };
  auto rdBL = [&](int c) {   // n 0..1
    const char* b = LB + 98304 + c * 16384;
    #pragma unroll
    for (int n = 0; n < 2; ++n)
      #pragma unroll
      for (int ks = 0; ks < 2; ++ks)
        Bf[n][ks] = *(const half8*)(b + boff[n][ks]);
  };
  auto rdBH = [&](int c) {   // n 2..3
    const char* b = LB + 98304 + c * 16384;
    #pragma unroll
    for (int n = 2; n < 4; ++n)
      #pragma unroll
      for (int ks = 0; ks < 2; ++ks)
        Bf[n][ks] = *(const half8*)(b + boff[n][ks]);
  };
  auto mfALBL = [&]() {
    #pragma unroll
    for (int m = 0; m < 4; ++m)
      #pragma unroll
      for (int n = 0; n < 2; ++n)
        #pragma unroll
        for (int ks = 0; ks < 2; ++ks)
          acc[m][n] = __builtin_amdgcn_mfma_f32_16x16x32_f16(A[m][ks], Bf[n][ks], acc[m][n], 0, 0, 0);
  };
  auto mfAHBL = [&]() {
    #pragma unroll
    for (int m = 4; m < 8; ++m)
      #pragma unroll
      for (int n = 0; n < 2; ++n)
        #pragma unroll
        for (int ks = 0; ks < 2; ++ks)
          acc[m][n] = __builtin_amdgcn_mfma_f32_16x16x32_f16(A[m][ks], Bf[n][ks], acc[m][n], 0, 0, 0);
  };
  auto mfALBH = [&]() {
    #pragma unroll
    for (int m = 0; m < 4; ++m)
      #pragma unroll
      for (int n = 2; n < 4; ++n)
        #pragma unroll
        for (int ks = 0; ks < 2; ++ks)
          acc[m][n] = __builtin_amdgcn_mfma_f32_16x16x32_f16(A[m][ks], Bf[n][ks], acc[m][n], 0, 0, 0);
  };
  auto mfAHBH = [&]() {
    #pragma unroll
    for (int m = 4; m < 8; ++m)
      #pragma unroll
      for (int n = 2; n < 4; ++n)
        #pragma unroll
        for (int ks = 0; ks < 2; ++ks)
          acc[m][n] = __builtin_amdgcn_mfma_f32_16x16x32_f16(A[m][ks], Bf[n][ks], acc[m][n], 0, 0, 0);
  };

  // ---- prologue: stage tile0 -> buf0, tile1 -> buf1 (12 loads each) ----
  #pragma unroll
  for (int k = 0; k < 8; ++k) stA(0, k);
  #pragma unroll
  for (int k = 0; k < 4; ++k) stB(0, k);
  advance();
  #pragma unroll
  for (int k = 0; k < 8; ++k) stA(1, k);
  #pragma unroll
  for (int k = 0; k < 4; ++k) stB(1, k);
  advance();
  VMCNT(12);                 // tile0 resident (tile1's 12 in flight)
  BARRIER;
  rdAL(0); rdBL(0);

  // ---- main loop: tiles 0..29, staging t+2 -> buf c2 ----
  int c0 = 0;
  #pragma unroll 1
  for (int t = 0; t < 30; ++t) {
    const int c1 = (c0 == 2) ? 0 : c0 + 1;
    const int c2 = (c1 == 2) ? 0 : c1 + 1;

    // P0: read AH(t) [used P1]; stage A0-2(t+2)
    rdAH(c0);
    stA(c2, 0); stA(c2, 1); stA(c2, 2);
    BARRIER;
    PRIO1; mfALBL(); PRIO0;

    // P1: read BH(t) [used P2]; stage A3-5(t+2); vmcnt(6): t+1 fully resident
    rdBH(c0);
    stA(c2, 3); stA(c2, 4); stA(c2, 5);
    VMCNT(6);
    BARRIER;
    PRIO1; mfAHBL(); PRIO0;

    // P2: read BL(t+1) [used P0(t+1)]; stage A6,A7,B0(t+2)
    rdBL(c1);
    stA(c2, 6); stA(c2, 7); stB(c2, 0);
    BARRIER;
    PRIO1; mfALBH(); PRIO0;

    // P3: read AL(t+1) [used P0(t+1)]; stage B1-3(t+2)
    rdAL(c1);
    stB(c2, 1); stB(c2, 2); stB(c2, 3);
    advance();
    BARRIER;
    PRIO1; mfAHBH(); PRIO0;

    c0 = c1;
  }

  // ---- tail: tile 30 (c0=0) and tile 31 (c1=1), no staging ----
  {
    rdAH(0);
    BARRIER;
    PRIO1; mfALBL(); PRIO0;
    rdBH(0);
    VMCNT(0);                 // tile31's 12 resident
    BARRIER;
    PRIO1; mfAHBL(); PRIO0;
    rdBL(1);
    BARRIER;
    PRIO1; mfALBH(); PRIO0;
    rdAL(1);
    BARRIER;
    PRIO1; mfAHBH(); PRIO0;
    // tile 31: pure compute
    rdAH(1); rdBH(1);
    mfALBL(); mfAHBL(); mfALBH(); mfAHBH();
  }

  // ---- epilogue: bias add, f32 preds, f16 predsh, rowsum partials ----
  float rp[8][4] = {};
  #pragma unroll
  for (int m = 0; m < 8; ++m) {
    #pragma unroll
    for (int n = 0; n < 4; ++n) {
      f32x4 d = acc[m][n];
      int gc = bn0 + wn * 64 + n * 16 + (lane & 15);
      float bias = (gc < C_) ? bmv[gc] : 0.f;
      #pragma unroll
      for (int j = 0; j < 4; ++j) {
        int gr = bm0 + wm * 128 + m * 16 + (lane >> 4) * 4 + j;
        float val = d[j] + bias;
        predsh[(size_t)gr * CP + gc] = (_Float16)val;
        if (gc < C_) preds[(size_t)gr * C_ + gc] = val;
        rp[m][j] += val;
      }
    }
  }
  #pragma unroll
  for (int m = 0; m < 8; ++m) {
    #pragma unroll
    for (int j = 0; j < 4; ++j) {
      float s = rp[m][j];
      s += __shfl_xor(s, 1); s += __shfl_xor(s, 2);
      s += __shfl_xor(s, 4); s += __shfl_xor(s, 8);
      if ((lane & 15) == 0) {
        int gr = bm0 + wm * 128 + m * 16 + (lane >> 4) * 4 + j;
        atomicAdd(&rowsum[gr], s);
      }
    }
  }
}

// ---------------- gating GEMM: same template, BM=BN=128, 4 waves 64x64 ----------------
__global__ __launch_bounds__(256, 1) void gemm2_kernel(
    const _Float16* __restrict__ predsh, const _Float16* __restrict__ uvh,
    const float* __restrict__ wv, float* __restrict__ scores)
{
  // A bufs (128x64 = 16KB) at c*16384 ; B bufs at 49152 + c*16384
  __shared__ _Float16 lds2[(3 * 16384 + 3 * 16384) / 2];   // 96 KB
  char* const LB = (char*)lds2;
  const int tid  = threadIdx.x;
  const int lane = tid & 63;
  const int w    = tid >> 6;
  const int wm   = w >> 1, wn = w & 1;   // wave tile 64x64
  const int bm0  = blockIdx.x * 128;
  const int bn0  = blockIdx.y * 128;

  f32x4 acc[4][4] = {};

  const int trow = tid >> 3;
  const int swzc = (((tid & 7) << 4) ^ ((trow & 7) << 4)) >> 1;
  const _Float16* pA = predsh + (size_t)(bm0 + trow) * CP + swzc;
  const _Float16* pB = uvh    + (size_t)(bn0 + trow) * CP + swzc;

  int aoff[4][2], boff[4][2];
  #pragma unroll
  for (int m = 0; m < 4; ++m)
    #pragma unroll
    for (int ks = 0; ks < 2; ++ks) {
      int ra = wm * 64 + m * 16 + (lane & 15);
      int kb = ks * 64 + (lane >> 4) * 16;
      aoff[m][ks] = ra * 128 + (kb ^ ((ra & 7) << 4));
    }
  #pragma unroll
  for (int n = 0; n < 4; ++n)
    #pragma unroll
    for (int ks = 0; ks < 2; ++ks) {
      int rb = wn * 64 + n * 16 + (lane & 15);
      int kb = ks * 64 + (lane >> 4) * 16;
      boff[n][ks] = rb * 128 + (kb ^ ((rb & 7) << 4));
    }

  half8 A[4][2], Bf[4][2];

  auto stA = [&](int c, int k) {
    gload16(pA + (size_t)k * 32 * CP, LB + c * 16384 + k * 4096 + w * 1024);
  };
  auto stB = [&](int c, int k) {
    gload16(pB + (size_t)k * 32 * CP, LB + 49152 + c * 16384 + k * 4096 + w * 1024);
  };
  auto advance = [&]() { pA += 64; pB += 64; };

  auto rdAL = [&](int c) {
    const char* b = LB + c * 16384;
    #pragma unroll
    for (int m = 0; m < 2; ++m)
      #pragma unroll
      for (int ks = 0; ks < 2; ++ks)
        A[m][ks] = *(const half8*)(b + aoff[m][ks]);
  };
  auto rdAH = [&](int c) {
    const char* b = LB + c * 16384;
    #pragma unroll
    for (int m = 2; m < 4; ++m)
      #pragma unroll
      for (int ks = 0; ks < 2; ++ks)
        A[m][ks] = *(const half8*)(b + aoff[m][ks]);
  };
  auto rdBL = [&](int c) {
    const char* b = LB + 49152 + c * 16384;
    #pragma unroll
    for (int n = 0; n < 2; ++n)
      #pragma unroll
      for (int ks = 0; ks < 2; ++ks)
        Bf[n][ks] = *(const half8*)(b + boff[n][ks]);
  };
  auto rdBH = [&](int c) {
    const char* b = LB + 49152 + c * 16384;
    #pragma unroll
    for (int n = 2; n < 4; ++n)
      #pragma unroll
      for (int ks = 0; ks < 2; ++ks)
        Bf[n][ks] = *(const half8*)(b + boff[n][ks]);
  };
  auto mf = [&](int mlo, int nlo) {
    #pragma unroll
    for (int m = 0; m < 2; ++m)
      #pragma unroll
      for (int n = 0; n < 2; ++n)
        #pragma unroll
        for (int ks = 0; ks < 2; ++ks)
          acc[mlo + m][nlo + n] = __builtin_amdgcn_mfma_f32_16x16x32_f16(
              A[mlo + m][ks], Bf[nlo + n][ks], acc[mlo + m][nlo + n], 0, 0, 0);
  };

  // prologue
  #pragma unroll
  for (int k = 0; k < 4; ++k) stA(0, k);
  #pragma unroll
  for (int k = 0; k < 4; ++k) stB(0, k);
  advance();
  #pragma unroll
  for (int k = 0; k < 4; ++k) stA(1, k);
  #pragma unroll
  for (int k = 0; k < 4; ++k) stB(1, k);
  advance();
  VMCNT(8);
  BARRIER;
  rdAL(0); rdBL(0);

  int c0 = 0;
  #pragma unroll 1
  for (int t = 0; t < 14; ++t) {   // NT=16, loop stages t+2 <= 15
    const int c1 = (c0 == 2) ? 0 : c0 + 1;
    const int c2 = (c1 == 2) ? 0 : c1 + 1;

    rdAH(c0);  stA(c2, 0); stA(c2, 1);
    BARRIER;
    PRIO1; mf(0, 0); PRIO0;

    rdBH(c0);  stA(c2, 2); stA(c2, 3);
    VMCNT(4);
    BARRIER;
    PRIO1; mf(2, 0); PRIO0;

    rdBL(c1);  stB(c2, 0); stB(c2, 1);
    BARRIER;
    PRIO1; mf(0, 2); PRIO0;

    rdAL(c1);  stB(c2, 2); stB(c2, 3);
    advance();
    BARRIER;
    PRIO1; mf(2, 2); PRIO0;

    c0 = c1;
  }
  // tail: tiles 14 (c0=14%3=2) and 15 (c1=0)
  {
    const int c0t = 2, c1t = 0;
    rdAH(c0t);
    BARRIER;
    PRIO1; mf(0, 0); PRIO0;
    rdBH(c0t);
    VMCNT(0);
    BARRIER;
    PRIO1; mf(2, 0); PRIO0;
    rdBL(c1t);
    BARRIER;
    PRIO1; mf(0, 2); PRIO0;
    rdAL(c1t);
    BARRIER;
    PRIO1; mf(2, 2); PRIO0;
    rdAH(c1t); rdBH(c1t);
    mf(0, 0); mf(2, 0); mf(0, 2); mf(2, 2);
  }

  // epilogue: gated = tanh(e_u)*sigmoid(e_v)*w_q ; per-row score partials
  float sp[4][4] = {};
  #pragma unroll
  for (int mi = 0; mi < 4; ++mi) {
    #pragma unroll
    for (int ni = 0; ni < 4; ++ni) {
      f32x4 d = acc[mi][ni];
      int gc = bn0 + wn * 64 + ni * 16 + (lane & 15);   // even=u col, odd=v col
      float wq = wv[gc >> 1];
      bool even = ((gc & 1) == 0);
      #pragma unroll
      for (int j = 0; j < 4; ++j) {
        float t  = d[j];
        float pr = __shfl_xor(t, 1);
        float th = 2.f / (1.f + __expf(-2.f * t)) - 1.f;
        float sg = 1.f / (1.f + __expf(-pr));
        sp[mi][j] += even ? (th * sg * wq) : 0.f;
      }
    }
  }
  #pragma unroll
  for (int mi = 0; mi < 4; ++mi) {
    #pragma unroll
    for (int j = 0; j < 4; ++j) {
      float s = sp[mi][j];
      s += __shfl_xor(s, 1); s += __shfl_xor(s, 2);
      s += __shfl_xor(s, 4); s += __shfl_xor(s, 8);
      if ((lane & 15) == 0) {
        int gr = bm0 + wm * 64 + mi * 16 + (lane >> 4) * 4 + j;
        atomicAdd(&scores[gr], s);
      }
    }
  }
}

// ---------------- final: softmax over scores, weighted rowsum ----------------
__global__ __launch_bounds__(1024) void final_kernel(
    const float* __restrict__ scores, const float* __restrict__ rowsum,
    float* __restrict__ out)
{
  __shared__ float red[16], red2[16];
  const int t = threadIdx.x;
  const int lane = t & 63, wid = t >> 6;
  float s[8];
  float m = -3.4e38f;
  #pragma unroll
  for (int i = 0; i < 8; ++i) { s[i] = scores[t + i * 1024]; m = fmaxf(m, s[i]); }
  #pragma unroll
  for (int off = 1; off < 64; off <<= 1) m = fmaxf(m, __shfl_xor(m, off));
  if (lane == 0) red[wid] = m;
  __syncthreads();
  #pragma unroll
  for (int i = 0; i < 16; ++i) m = fmaxf(m, red[i]);
  __syncthreads();

  float se = 0.f, sr = 0.f;
  #pragma unroll
  for (int i = 0; i < 8; ++i) {
    float e = __expf(s[i] - m);
    se += e;
    sr += e * rowsum[t + i * 1024];
  }
  #pragma unroll
  for (int off = 1; off < 64; off <<= 1) { se += __shfl_xor(se, off); sr += __shfl_xor(sr, off); }
  if (lane == 0) { red[wid] = se; red2[wid] = sr; }
  __syncthreads();
  if (t == 0) {
    float tse = 0.f, tsr = 0.f;
    for (int i = 0; i < 16; ++i) { tse += red[i]; tsr += red2[i]; }
    out[0] = tsr / tse;
  }
}

extern "C" void kernel_launch(void* const* d_in, const int* in_sizes, int n_in,
                              void* d_out, int out_size, void* d_ws, size_t ws_size,
                              hipStream_t stream)
{
  const float* x   = (const float*)d_in[0];
  const float* Wm  = (const float*)d_in[1];
  const float* bmv = (const float*)d_in[2];
  const float* u   = (const float*)d_in[3];
  const float* v   = (const float*)d_in[4];
  const float* wv  = (const float*)d_in[5];
  float* out = (float*)d_out;

  if (ws_size < WS_NEED) return;

  char* ws = (char*)d_ws;
  _Float16* xh     = (_Float16*)(ws + OFF_XH);
  _Float16* wh     = (_Float16*)(ws + OFF_WH);
  _Float16* uvh    = (_Float16*)(ws + OFF_UVH);
  _Float16* predsh = (_Float16*)(ws + OFF_PH);
  float*    scores = (float*)(ws + OFF_SC);
  float*    rowsum = (float*)(ws + OFF_RS);

  prep_kernel<<<2048, 256, 0, stream>>>(x, Wm, u, v, xh, wh, uvh, scores, rowsum);
  gemm1_kernel<<<dim3(32, 8), 256, 0, stream>>>(xh, wh, bmv, out, predsh, rowsum);
  gemm2_kernel<<<dim3(64, 4), 256, 0, stream>>>(predsh, uvh, wv, scores);
  final_kernel<<<1, 1024, 0, stream>>>(scores, rowsum, out + (size_t)B_ * C_);
}

// Round 8
// 94.861 us; speedup vs baseline: 1.0864x; 1.0864x over previous
//
#include <hip/hip_runtime.h>
#include <hip/hip_fp16.h>

typedef _Float16 half8 __attribute__((ext_vector_type(8)));
typedef float f32x4 __attribute__((ext_vector_type(4)));

#define B_   8192
#define DIN  2048
#define C_   1000
#define CP   1024
#define NP2  512   // u,v interleaved rows

// ---- workspace layout (bytes) ----
static const size_t OFF_XH  = 0;                                   // xh  [8192][2048] f16
static const size_t OFF_WH  = OFF_XH  + (size_t)B_ * DIN * 2;      // wh  [1024][2048] f16 (rows>=1000 zero)
static const size_t OFF_UVH = OFF_WH  + (size_t)CP * DIN * 2;      // uvh [512][1024]  f16
static const size_t OFF_PH  = OFF_UVH + (size_t)NP2 * CP * 2;      // predsh [8192][1024] f16
static const size_t OFF_SC  = OFF_PH  + (size_t)B_ * CP * 2;       // scores [8192] f32
static const size_t OFF_RS  = OFF_SC  + (size_t)B_ * 4;            // rowsum [8192] f32
static const size_t WS_NEED = OFF_RS  + (size_t)B_ * 4;

#define FENCE asm volatile("" ::: "memory")
#define BARRIER do { FENCE; __builtin_amdgcn_s_barrier(); FENCE; } while (0)
#define VMCNT(n) asm volatile("s_waitcnt vmcnt(" #n ")" ::: "memory")
#define PRIO1 __builtin_amdgcn_s_setprio(1)
#define PRIO0 __builtin_amdgcn_s_setprio(0)

__device__ __forceinline__ void gload16(const void* g, void* l) {
  __builtin_amdgcn_global_load_lds(
      (const __attribute__((address_space(1))) void*)g,
      (__attribute__((address_space(3))) void*)l, 16, 0, 0);
}

// ---------------- prep: f32 -> f16 conversions + zeroing (r5-validated) ----------------
__global__ __launch_bounds__(256) void prep_kernel(
    const float* __restrict__ x, const float* __restrict__ Wm,
    const float* __restrict__ u, const float* __restrict__ v,
    _Float16* __restrict__ xh, _Float16* __restrict__ wh,
    _Float16* __restrict__ uvh, float* __restrict__ scores,
    float* __restrict__ rowsum)
{
  const long NX  = (long)B_ * DIN / 8;
  const long NW  = (long)CP * DIN / 8;
  const long NUV = (long)NP2 * CP / 8;
  const long NZ  = 2 * (long)B_ / 8;
  const long T   = NX + NW + NUV + NZ;
  for (long idx = (long)blockIdx.x * blockDim.x + threadIdx.x; idx < T;
       idx += (long)gridDim.x * blockDim.x) {
    if (idx < NX) {
      long e = idx * 8;
      float4 p0 = *(const float4*)(x + e);
      float4 p1 = *(const float4*)(x + e + 4);
      half8 h;
      h[0] = (_Float16)p0.x; h[1] = (_Float16)p0.y; h[2] = (_Float16)p0.z; h[3] = (_Float16)p0.w;
      h[4] = (_Float16)p1.x; h[5] = (_Float16)p1.y; h[6] = (_Float16)p1.z; h[7] = (_Float16)p1.w;
      *(half8*)(xh + e) = h;
    } else if (idx < NX + NW) {
      long e = (idx - NX) * 8;
      int row = (int)(e >> 11);
      half8 h;
      if (row < C_) {
        float4 p0 = *(const float4*)(Wm + e);
        float4 p1 = *(const float4*)(Wm + e + 4);
        h[0] = (_Float16)p0.x; h[1] = (_Float16)p0.y; h[2] = (_Float16)p0.z; h[3] = (_Float16)p0.w;
        h[4] = (_Float16)p1.x; h[5] = (_Float16)p1.y; h[6] = (_Float16)p1.z; h[7] = (_Float16)p1.w;
      } else {
        h = (half8)(_Float16)0.f;
      }
      *(half8*)(wh + e) = h;
    } else if (idx < NX + NW + NUV) {
      long e = (idx - NX - NW) * 8;
      int j = (int)(e >> 10);
      int k = (int)(e & 1023);
      const float* src = (j & 1) ? v : u;
      int p = j >> 1;
      half8 h;
      #pragma unroll
      for (int t = 0; t < 8; ++t) {
        int kk = k + t;
        h[t] = (kk < C_) ? (_Float16)src[(size_t)p * C_ + kk] : (_Float16)0.f;
      }
      *(half8*)(uvh + e) = h;
    } else {
      long e = (idx - NX - NW - NUV) * 8;
      float4 z = {0.f, 0.f, 0.f, 0.f};
      if (e < B_) {
        *(float4*)(scores + e) = z; *(float4*)(scores + e + 4) = z;
      } else {
        long r = e - B_;
        *(float4*)(rowsum + r) = z; *(float4*)(rowsum + r + 4) = z;
      }
    }
  }
}

// ---------------- main GEMM: preds = xh @ wh^T + bm ----------------
// 256x128 tile, BK=64, 512 threads = 8 waves (4M x 2N), wave tile 64x64.
// ONE fat MFMA cluster (32 MFMA = ~1240 cyc/SIMD) per K-tile; 2 barriers/tile
// (vs r5's 4 phases x ~300cyc fixed overhead each). Reads for tile t+1 issued
// under tile t's MFMA (full-tile lgkm slack); fragment regs double-buffered
// (Aa/Ba <-> Ab/Bb). 3-buffer LDS, stage t+2 while computing t, single
// counted vmcnt(6) per tile (FIFO: t+1's 6 retire, t+2's 6 in flight).
// Hazards: vmcnt -> BARRIER -> read (cross-wave gload visibility);
// reads of old buffer lgkm-complete before MFMA, which precedes the barrier
// that precedes its overwrite.
__global__ __launch_bounds__(512, 2) void gemm1_kernel(
    const _Float16* __restrict__ xh, const _Float16* __restrict__ wh,
    const float* __restrict__ bmv, float* __restrict__ preds,
    _Float16* __restrict__ predsh, float* __restrict__ rowsum)
{
  // A bufs (256x64 f16 = 32KB) at c*32768 ; B bufs (128x64 = 16KB) at 98304 + c*16384
  __shared__ _Float16 lds[(3 * 32768 + 3 * 16384) / 2];   // 144 KB
  char* const LB = (char*)lds;
  const int tid  = threadIdx.x;
  const int lane = tid & 63;
  const int w    = tid >> 6;       // 0..7
  const int wm   = w >> 1;         // 0..3 (M quarter: 64 rows)
  const int wn   = w & 1;          // 0..1 (N half: 64 cols)
  const int bm0  = blockIdx.x * 256;
  const int bn0  = blockIdx.y * 128;

  f32x4 acc[4][4] = {};

  // staging: 512 threads; A rows trow+64k (k=0..3), B rows trow+64k (k=0..1);
  // pre-swizzled global source (k*64 % 8 == 0 -> swizzle k-independent),
  // linear gload_lds dest = base + k*8192 + w*1024 (+lane*16 by HW).
  const int trow = tid >> 3;                       // 0..63
  const int swzc = (((tid & 7) << 4) ^ ((trow & 7) << 4)) >> 1;  // f16 units
  const _Float16* pA = xh + (size_t)(bm0 + trow) * DIN + swzc;
  const _Float16* pB = wh + (size_t)(bn0 + trow) * DIN + swzc;

  // ds_read fragment byte offsets (within one A / B buffer)
  int aoff[4][2], boff[4][2];
  #pragma unroll
  for (int m = 0; m < 4; ++m)
    #pragma unroll
    for (int ks = 0; ks < 2; ++ks) {
      int ra = wm * 64 + m * 16 + (lane & 15);
      int kb = ks * 64 + (lane >> 4) * 16;
      aoff[m][ks] = ra * 128 + (kb ^ ((ra & 7) << 4));
    }
  #pragma unroll
  for (int n = 0; n < 4; ++n)
    #pragma unroll
    for (int ks = 0; ks < 2; ++ks) {
      int rb = wn * 64 + n * 16 + (lane & 15);
      int kb = ks * 64 + (lane >> 4) * 16;
      boff[n][ks] = rb * 128 + (kb ^ ((rb & 7) << 4));
    }

  half8 Aa[4][2], Ba[4][2], Ab[4][2], Bb[4][2];   // double-buffered frags

  auto stage = [&](int c) {   // 6 gloads: full tile into buf c
    #pragma unroll
    for (int k = 0; k < 4; ++k)
      gload16(pA + (size_t)k * 64 * DIN, LB + c * 32768 + k * 8192 + w * 1024);
    #pragma unroll
    for (int k = 0; k < 2; ++k)
      gload16(pB + (size_t)k * 64 * DIN, LB + 98304 + c * 16384 + k * 8192 + w * 1024);
    pA += 64; pB += 64;
  };
  auto rdFrag = [&](int c, half8 (&A)[4][2], half8 (&Bf)[4][2]) {
    const char* ab = LB + c * 32768;
    const char* bb = LB + 98304 + c * 16384;
    #pragma unroll
    for (int m = 0; m < 4; ++m)
      #pragma unroll
      for (int ks = 0; ks < 2; ++ks)
        A[m][ks] = *(const half8*)(ab + aoff[m][ks]);
    #pragma unroll
    for (int n = 0; n < 4; ++n)
      #pragma unroll
      for (int ks = 0; ks < 2; ++ks)
        Bf[n][ks] = *(const half8*)(bb + boff[n][ks]);
  };
  auto mfAll = [&](half8 (&A)[4][2], half8 (&Bf)[4][2]) {
    PRIO1;
    #pragma unroll
    for (int m = 0; m < 4; ++m)
      #pragma unroll
      for (int n = 0; n < 4; ++n)
        #pragma unroll
        for (int ks = 0; ks < 2; ++ks)
          acc[m][n] = __builtin_amdgcn_mfma_f32_16x16x32_f16(A[m][ks], Bf[n][ks], acc[m][n], 0, 0, 0);
    PRIO0;
  };

  // ---- prologue: stage tile0 -> buf0, tile1 -> buf1 ----
  stage(0);
  stage(1);
  VMCNT(6);                  // tile0 resident (tile1's 6 in flight)
  BARRIER;
  rdFrag(0, Aa, Ba);         // frags(tile0)

  // ---- main loop: 2 tiles per iteration, tiles 0..29 ----
  int c0 = 0;
  #pragma unroll 1
  for (int t = 0; t < 30; t += 2) {
    const int c1 = (c0 == 2) ? 0 : c0 + 1;
    const int c2 = (c1 == 2) ? 0 : c1 + 1;

    // tile t: stage t+2 -> c2; t+1 resident; read frags(t+1); MFMA(t)
    stage(c2);
    VMCNT(6);
    BARRIER;
    rdFrag(c1, Ab, Bb);
    mfAll(Aa, Ba);
    BARRIER;

    // tile t+1: stage t+3 -> c0; t+2 resident; read frags(t+2); MFMA(t+1)
    stage(c0);
    VMCNT(6);
    BARRIER;
    rdFrag(c2, Aa, Ba);
    mfAll(Ab, Bb);
    BARRIER;

    c0 = c2;
  }

  // ---- tail: tiles 30 (buf0, frags in Aa/Ba) and 31 (buf1) ----
  VMCNT(0);                  // tile31's 6 resident
  BARRIER;
  rdFrag(1, Ab, Bb);
  mfAll(Aa, Ba);             // tile 30
  mfAll(Ab, Bb);             // tile 31

  // ---- epilogue: bias add, f32 preds, f16 predsh, rowsum partials ----
  float rp[4][4] = {};
  #pragma unroll
  for (int m = 0; m < 4; ++m) {
    #pragma unroll
    for (int n = 0; n < 4; ++n) {
      f32x4 d = acc[m][n];
      int gc = bn0 + wn * 64 + n * 16 + (lane & 15);
      float bias = (gc < C_) ? bmv[gc] : 0.f;
      #pragma unroll
      for (int j = 0; j < 4; ++j) {
        int gr = bm0 + wm * 64 + m * 16 + (lane >> 4) * 4 + j;
        float val = d[j] + bias;
        predsh[(size_t)gr * CP + gc] = (_Float16)val;
        if (gc < C_) preds[(size_t)gr * C_ + gc] = val;
        rp[m][j] += val;
      }
    }
  }
  #pragma unroll
  for (int m = 0; m < 4; ++m) {
    #pragma unroll
    for (int j = 0; j < 4; ++j) {
      float s = rp[m][j];
      s += __shfl_xor(s, 1); s += __shfl_xor(s, 2);
      s += __shfl_xor(s, 4); s += __shfl_xor(s, 8);
      if ((lane & 15) == 0) {
        int gr = bm0 + wm * 64 + m * 16 + (lane >> 4) * 4 + j;
        atomicAdd(&rowsum[gr], s);
      }
    }
  }
}

// ---------------- gating GEMM (r7-validated: BM=BN=128, 4 waves 64x64) ----------------
__global__ __launch_bounds__(256, 1) void gemm2_kernel(
    const _Float16* __restrict__ predsh, const _Float16* __restrict__ uvh,
    const float* __restrict__ wv, float* __restrict__ scores)
{
  // A bufs (128x64 = 16KB) at c*16384 ; B bufs at 49152 + c*16384
  __shared__ _Float16 lds2[(3 * 16384 + 3 * 16384) / 2];   // 96 KB
  char* const LB = (char*)lds2;
  const int tid  = threadIdx.x;
  const int lane = tid & 63;
  const int w    = tid >> 6;
  const int wm   = w >> 1, wn = w & 1;   // wave tile 64x64
  const int bm0  = blockIdx.x * 128;
  const int bn0  = blockIdx.y * 128;

  f32x4 acc[4][4] = {};

  const int trow = tid >> 3;
  const int swzc = (((tid & 7) << 4) ^ ((trow & 7) << 4)) >> 1;
  const _Float16* pA = predsh + (size_t)(bm0 + trow) * CP + swzc;
  const _Float16* pB = uvh    + (size_t)(bn0 + trow) * CP + swzc;

  int aoff[4][2], boff[4][2];
  #pragma unroll
  for (int m = 0; m < 4; ++m)
    #pragma unroll
    for (int ks = 0; ks < 2; ++ks) {
      int ra = wm * 64 + m * 16 + (lane & 15);
      int kb = ks * 64 + (lane >> 4) * 16;
      aoff[m][ks] = ra * 128 + (kb ^ ((ra & 7) << 4));
    }
  #pragma unroll
  for (int n = 0; n < 4; ++n)
    #pragma unroll
    for (int ks = 0; ks < 2; ++ks) {
      int rb = wn * 64 + n * 16 + (lane & 15);
      int kb = ks * 64 + (lane >> 4) * 16;
      boff[n][ks] = rb * 128 + (kb ^ ((rb & 7) << 4));
    }

  half8 A[4][2], Bf[4][2];

  auto stA = [&](int c, int k) {
    gload16(pA + (size_t)k * 32 * CP, LB + c * 16384 + k * 4096 + w * 1024);
  };
  auto stB = [&](int c, int k) {
    gload16(pB + (size_t)k * 32 * CP, LB + 49152 + c * 16384 + k * 4096 + w * 1024);
  };
  auto advance = [&]() { pA += 64; pB += 64; };

  auto rdAL = [&](int c) {
    const char* b = LB + c * 16384;
    #pragma unroll
    for (int m = 0; m < 2; ++m)
      #pragma unroll
      for (int ks = 0; ks < 2; ++ks)
        A[m][ks] = *(const half8*)(b + aoff[m][ks]);
  };
  auto rdAH = [&](int c) {
    const char* b = LB + c * 16384;
    #pragma unroll
    for (int m = 2; m < 4; ++m)
      #pragma unroll
      for (int ks = 0; ks < 2; ++ks)
        A[m][ks] = *(const half8*)(b + aoff[m][ks]);
  };
  auto rdBL = [&](int c) {
    const char* b = LB + 49152 + c * 16384;
    #pragma unroll
    for (int n = 0; n < 2; ++n)
      #pragma unroll
      for (int ks = 0; ks < 2; ++ks)
        Bf[n][ks] = *(const half8*)(b + boff[n][ks]);
  };
  auto rdBH = [&](int c) {
    const char* b = LB + 49152 + c * 16384;
    #pragma unroll
    for (int n = 2; n < 4; ++n)
      #pragma unroll
      for (int ks = 0; ks < 2; ++ks)
        Bf[n][ks] = *(const half8*)(b + boff[n][ks]);
  };
  auto mf = [&](int mlo, int nlo) {
    #pragma unroll
    for (int m = 0; m < 2; ++m)
      #pragma unroll
      for (int n = 0; n < 2; ++n)
        #pragma unroll
        for (int ks = 0; ks < 2; ++ks)
          acc[mlo + m][nlo + n] = __builtin_amdgcn_mfma_f32_16x16x32_f16(
              A[mlo + m][ks], Bf[nlo + n][ks], acc[mlo + m][nlo + n], 0, 0, 0);
  };

  // prologue
  #pragma unroll
  for (int k = 0; k < 4; ++k) stA(0, k);
  #pragma unroll
  for (int k = 0; k < 4; ++k) stB(0, k);
  advance();
  #pragma unroll
  for (int k = 0; k < 4; ++k) stA(1, k);
  #pragma unroll
  for (int k = 0; k < 4; ++k) stB(1, k);
  advance();
  VMCNT(8);
  BARRIER;
  rdAL(0); rdBL(0);

  int c0 = 0;
  #pragma unroll 1
  for (int t = 0; t < 14; ++t) {   // NT=16, loop stages t+2 <= 15
    const int c1 = (c0 == 2) ? 0 : c0 + 1;
    const int c2 = (c1 == 2) ? 0 : c1 + 1;

    rdAH(c0);  stA(c2, 0); stA(c2, 1);
    BARRIER;
    PRIO1; mf(0, 0); PRIO0;

    rdBH(c0);  stA(c2, 2); stA(c2, 3);
    VMCNT(4);
    BARRIER;
    PRIO1; mf(2, 0); PRIO0;

    rdBL(c1);  stB(c2, 0); stB(c2, 1);
    BARRIER;
    PRIO1; mf(0, 2); PRIO0;

    rdAL(c1);  stB(c2, 2); stB(c2, 3);
    advance();
    BARRIER;
    PRIO1; mf(2, 2); PRIO0;

    c0 = c1;
  }
  // tail: tiles 14 (c0=2) and 15 (c1=0)
  {
    const int c0t = 2, c1t = 0;
    rdAH(c0t);
    BARRIER;
    PRIO1; mf(0, 0); PRIO0;
    rdBH(c0t);
    VMCNT(0);
    BARRIER;
    PRIO1; mf(2, 0); PRIO0;
    rdBL(c1t);
    BARRIER;
    PRIO1; mf(0, 2); PRIO0;
    rdAL(c1t);
    BARRIER;
    PRIO1; mf(2, 2); PRIO0;
    rdAH(c1t); rdBH(c1t);
    mf(0, 0); mf(2, 0); mf(0, 2); mf(2, 2);
  }

  // epilogue: gated = tanh(e_u)*sigmoid(e_v)*w_q ; per-row score partials
  float sp[4][4] = {};
  #pragma unroll
  for (int mi = 0; mi < 4; ++mi) {
    #pragma unroll
    for (int ni = 0; ni < 4; ++ni) {
      f32x4 d = acc[mi][ni];
      int gc = bn0 + wn * 64 + ni * 16 + (lane & 15);   // even=u col, odd=v col
      float wq = wv[gc >> 1];
      bool even = ((gc & 1) == 0);
      #pragma unroll
      for (int j = 0; j < 4; ++j) {
        float t  = d[j];
        float pr = __shfl_xor(t, 1);
        float th = 2.f / (1.f + __expf(-2.f * t)) - 1.f;
        float sg = 1.f / (1.f + __expf(-pr));
        sp[mi][j] += even ? (th * sg * wq) : 0.f;
      }
    }
  }
  #pragma unroll
  for (int mi = 0; mi < 4; ++mi) {
    #pragma unroll
    for (int j = 0; j < 4; ++j) {
      float s = sp[mi][j];
      s += __shfl_xor(s, 1); s += __shfl_xor(s, 2);
      s += __shfl_xor(s, 4); s += __shfl_xor(s, 8);
      if ((lane & 15) == 0) {
        int gr = bm0 + wm * 64 + mi * 16 + (lane >> 4) * 4 + j;
        atomicAdd(&scores[gr], s);
      }
    }
  }
}

// ---------------- final: softmax over scores, weighted rowsum ----------------
__global__ __launch_bounds__(1024) void final_kernel(
    const float* __restrict__ scores, const float* __restrict__ rowsum,
    float* __restrict__ out)
{
  __shared__ float red[16], red2[16];
  const int t = threadIdx.x;
  const int lane = t & 63, wid = t >> 6;
  float s[8];
  float m = -3.4e38f;
  #pragma unroll
  for (int i = 0; i < 8; ++i) { s[i] = scores[t + i * 1024]; m = fmaxf(m, s[i]); }
  #pragma unroll
  for (int off = 1; off < 64; off <<= 1) m = fmaxf(m, __shfl_xor(m, off));
  if (lane == 0) red[wid] = m;
  __syncthreads();
  #pragma unroll
  for (int i = 0; i < 16; ++i) m = fmaxf(m, red[i]);
  __syncthreads();

  float se = 0.f, sr = 0.f;
  #pragma unroll
  for (int i = 0; i < 8; ++i) {
    float e = __expf(s[i] - m);
    se += e;
    sr += e * rowsum[t + i * 1024];
  }
  #pragma unroll
  for (int off = 1; off < 64; off <<= 1) { se += __shfl_xor(se, off); sr += __shfl_xor(sr, off); }
  if (lane == 0) { red[wid] = se; red2[wid] = sr; }
  __syncthreads();
  if (t == 0) {
    float tse = 0.f, tsr = 0.f;
    for (int i = 0; i < 16; ++i) { tse += red[i]; tsr += red2[i]; }
    out[0] = tsr / tse;
  }
}

extern "C" void kernel_launch(void* const* d_in, const int* in_sizes, int n_in,
                              void* d_out, int out_size, void* d_ws, size_t ws_size,
                              hipStream_t stream)
{
  const float* x   = (const float*)d_in[0];
  const float* Wm  = (const float*)d_in[1];
  const float* bmv = (const float*)d_in[2];
  const float* u   = (const float*)d_in[3];
  const float* v   = (const float*)d_in[4];
  const float* wv  = (const float*)d_in[5];
  float* out = (float*)d_out;

  if (ws_size < WS_NEED) return;

  char* ws = (char*)d_ws;
  _Float16* xh     = (_Float16*)(ws + OFF_XH);
  _Float16* wh     = (_Float16*)(ws + OFF_WH);
  _Float16* uvh    = (_Float16*)(ws + OFF_UVH);
  _Float16* predsh = (_Float16*)(ws + OFF_PH);
  float*    scores = (float*)(ws + OFF_SC);
  float*    rowsum = (float*)(ws + OFF_RS);

  prep_kernel<<<2048, 256, 0, stream>>>(x, Wm, u, v, xh, wh, uvh, scores, rowsum);
  gemm1_kernel<<<dim3(32, 8), 512, 0, stream>>>(xh, wh, bmv, out, predsh, rowsum);
  gemm2_kernel<<<dim3(64, 4), 256, 0, stream>>>(predsh, uvh, wv, scores);
  final_kernel<<<1, 1024, 0, stream>>>(scores, rowsum, out + (size_t)B_ * C_);
}

// Round 9
// 93.586 us; speedup vs baseline: 1.1012x; 1.0136x over previous
//
#include <hip/hip_runtime.h>
#include <hip/hip_fp16.h>

typedef _Float16 half8 __attribute__((ext_vector_type(8)));
typedef float f32x4 __attribute__((ext_vector_type(4)));

#define B_   8192
#define DIN  2048
#define C_   1000
#define CP   1024
#define NP2  512   // u,v interleaved rows

// ---- workspace layout (bytes) ---- (no xh: gemm1 reads f32 x directly)
static const size_t OFF_WH  = 0;                                   // wh  [1024][2048] f16 (rows>=1000 zero)
static const size_t OFF_UVH = OFF_WH  + (size_t)CP * DIN * 2;      // uvh [512][1024]  f16
static const size_t OFF_PH  = OFF_UVH + (size_t)NP2 * CP * 2;      // predsh [8192][1024] f16
static const size_t OFF_SC  = OFF_PH  + (size_t)B_ * CP * 2;       // scores [8192] f32
static const size_t OFF_RS  = OFF_SC  + (size_t)B_ * 4;            // rowsum [8192] f32
static const size_t WS_NEED = OFF_RS  + (size_t)B_ * 4;

#define FENCE asm volatile("" ::: "memory")
#define BARRIER do { FENCE; __builtin_amdgcn_s_barrier(); FENCE; } while (0)
#define VMCNT(n) asm volatile("s_waitcnt vmcnt(" #n ")" ::: "memory")
#define PRIO1 __builtin_amdgcn_s_setprio(1)
#define PRIO0 __builtin_amdgcn_s_setprio(0)

__device__ __forceinline__ void gload16(const void* g, void* l) {
  __builtin_amdgcn_global_load_lds(
      (const __attribute__((address_space(1))) void*)g,
      (__attribute__((address_space(3))) void*)l, 16, 0, 0);
}

// ---------------- prep: f32 -> f16 (Wm, u/v) + zeroing (r3-validated; no x) ----------------
__global__ __launch_bounds__(256) void prep_kernel(
    const float* __restrict__ Wm,
    const float* __restrict__ u, const float* __restrict__ v,
    _Float16* __restrict__ wh, _Float16* __restrict__ uvh,
    float* __restrict__ scores, float* __restrict__ rowsum)
{
  const long NW  = (long)CP * DIN / 8;      //   262,144
  const long NUV = (long)NP2 * CP / 8;      //    65,536
  const long NZ  = 2 * (long)B_ / 8;        //     2,048
  const long T   = NW + NUV + NZ;
  for (long idx = (long)blockIdx.x * blockDim.x + threadIdx.x; idx < T;
       idx += (long)gridDim.x * blockDim.x) {
    if (idx < NW) {
      long e = idx * 8;
      int row = (int)(e >> 11);
      half8 h;
      if (row < C_) {
        float4 p0 = *(const float4*)(Wm + e);
        float4 p1 = *(const float4*)(Wm + e + 4);
        h[0] = (_Float16)p0.x; h[1] = (_Float16)p0.y; h[2] = (_Float16)p0.z; h[3] = (_Float16)p0.w;
        h[4] = (_Float16)p1.x; h[5] = (_Float16)p1.y; h[6] = (_Float16)p1.z; h[7] = (_Float16)p1.w;
      } else {
        h = (half8)(_Float16)0.f;
      }
      *(half8*)(wh + e) = h;
    } else if (idx < NW + NUV) {
      long e = (idx - NW) * 8;
      int j = (int)(e >> 10);
      int k = (int)(e & 1023);
      const float* src = (j & 1) ? v : u;
      int p = j >> 1;
      half8 h;
      #pragma unroll
      for (int t = 0; t < 8; ++t) {
        int kk = k + t;
        h[t] = (kk < C_) ? (_Float16)src[(size_t)p * C_ + kk] : (_Float16)0.f;
      }
      *(half8*)(uvh + e) = h;
    } else {
      long e = (idx - NW - NUV) * 8;
      float4 z = {0.f, 0.f, 0.f, 0.f};
      if (e < B_) {
        *(float4*)(scores + e) = z; *(float4*)(scores + e + 4) = z;
      } else {
        long r = e - B_;
        *(float4*)(rowsum + r) = z; *(float4*)(rowsum + r + 4) = z;
      }
    }
  }
}

// ---------------- main GEMM: preds = x(f32) @ wh^T + bm ----------------
// A staged as RAW f32 via global_load_lds (no cvt at staging -> no r3/r6
// latency hazard); f32->f16 conversion happens at fragment-read time.
// BK=32 keeps the f32 A-tile in the proven 128B-row geometry (256x32xf32 =
// 32KB/buf, same XOR swizzle & conflict-free banks as the f16 BK=64 tile).
// B: 128x32 f16 = 8KB/buf, swizzle slot^((row>>1)&3) (2-way residual, free).
// 3 buffers (120KB), 512 thr = 8 waves (4M x 2N), wave tile 64x64.
// r8 fat-cluster skeleton at 64 K-tiles: per tile {stage(t+2) 5 loads ->
// vmcnt(5) [t+1 resident] -> barrier -> rdFrag(t+1)+cvt -> 16 MFMA(t) -> barrier}.
__global__ __launch_bounds__(512, 2) void gemm1_kernel(
    const float* __restrict__ x, const _Float16* __restrict__ wh,
    const float* __restrict__ bmv, float* __restrict__ preds,
    _Float16* __restrict__ predsh, float* __restrict__ rowsum)
{
  // A bufs (256 rows x 128B) at c*32768 ; B bufs (128 rows x 64B) at 98304 + c*8192
  __shared__ __align__(16) char LB[3 * 32768 + 3 * 8192];   // 120 KB
  const int tid  = threadIdx.x;
  const int lane = tid & 63;
  const int w    = tid >> 6;       // 0..7
  const int wm   = w >> 1;         // 0..3 (M quarter: 64 rows)
  const int wn   = w & 1;          // 0..1 (N half: 64 cols)
  const int bm0  = blockIdx.x * 256;
  const int bn0  = blockIdx.y * 128;

  f32x4 acc[4][4] = {};

  // A staging: 4 loads/tile; load k covers rows trow+64k; slot = 16B chunk.
  // Pre-swizzled source (row&7 == trow&7, k-independent), linear LDS dest.
  const int trow = tid >> 3;                         // 0..63
  const float* pAx = x + (size_t)(bm0 + trow) * DIN + (((tid & 7) ^ (trow & 7)) << 2);
  // B staging: 1 load/tile; row = tid>>2, slot = tid&3, swz slot^((row>>1)&3).
  const int brow = tid >> 2;                         // 0..127
  const _Float16* pBx = wh + (size_t)(bn0 + brow) * DIN + ((((tid & 3) ^ ((brow >> 1) & 3)) << 3));

  // fragment ds_read byte offsets
  int aoff[4][2], boff[4];
  #pragma unroll
  for (int m = 0; m < 4; ++m) {
    int ra = wm * 64 + m * 16 + (lane & 15);
    int c0 = (lane >> 4) * 2;                        // 16B chunk of f32 k-group
    aoff[m][0] = ra * 128 + (((c0)     ^ (ra & 7)) << 4);
    aoff[m][1] = ra * 128 + (((c0 + 1) ^ (ra & 7)) << 4);
  }
  #pragma unroll
  for (int n = 0; n < 4; ++n) {
    int rb = wn * 64 + n * 16 + (lane & 15);
    boff[n] = rb * 64 + ((((lane >> 4)) ^ ((rb >> 1) & 3)) << 4);
  }

  half8 Aa[4], Ba[4], Ab[4], Bb[4];   // double-buffered fragment sets

  auto stage = [&](int c) {   // 5 gloads: tile into buf c, then advance K
    #pragma unroll
    for (int k = 0; k < 4; ++k)
      gload16(pAx + (size_t)k * 64 * DIN, LB + c * 32768 + k * 8192 + w * 1024);
    gload16(pBx, LB + 98304 + c * 8192 + w * 1024);
    pAx += 32; pBx += 32;
  };
  auto rdFrag = [&](int c, half8 (&A)[4], half8 (&Bf)[4]) {
    const char* ab = LB + c * 32768;
    const char* bb = LB + 98304 + c * 8192;
    #pragma unroll
    for (int m = 0; m < 4; ++m) {
      f32x4 lo = *(const f32x4*)(ab + aoff[m][0]);
      f32x4 hi = *(const f32x4*)(ab + aoff[m][1]);
      half8 h;
      h[0] = (_Float16)lo[0]; h[1] = (_Float16)lo[1];
      h[2] = (_Float16)lo[2]; h[3] = (_Float16)lo[3];
      h[4] = (_Float16)hi[0]; h[5] = (_Float16)hi[1];
      h[6] = (_Float16)hi[2]; h[7] = (_Float16)hi[3];
      A[m] = h;
    }
    #pragma unroll
    for (int n = 0; n < 4; ++n)
      Bf[n] = *(const half8*)(bb + boff[n]);
  };
  auto mfAll = [&](half8 (&A)[4], half8 (&Bf)[4]) {
    PRIO1;
    #pragma unroll
    for (int m = 0; m < 4; ++m)
      #pragma unroll
      for (int n = 0; n < 4; ++n)
        acc[m][n] = __builtin_amdgcn_mfma_f32_16x16x32_f16(A[m], Bf[n], acc[m][n], 0, 0, 0);
    PRIO0;
  };

  // ---- prologue: stage tile0 -> buf0, tile1 -> buf1 ----
  stage(0);
  stage(1);
  VMCNT(5);                  // tile0 resident (tile1's 5 in flight)
  BARRIER;
  rdFrag(0, Aa, Ba);

  // ---- main loop: tiles 0..61, two per iteration; stages through tile 63 ----
  int c0 = 0;
  #pragma unroll 1
  for (int t = 0; t < 62; t += 2) {
    const int c1 = (c0 == 2) ? 0 : c0 + 1;
    const int c2 = (c1 == 2) ? 0 : c1 + 1;

    // tile t: stage t+2 -> c2; wait t+1 resident; read frags(t+1); MFMA(t)
    stage(c2);
    VMCNT(5);
    BARRIER;
    rdFrag(c1, Ab, Bb);
    mfAll(Aa, Ba);
    BARRIER;

    // tile t+1: stage t+3 -> c0; wait t+2 resident; read frags(t+2); MFMA(t+1)
    stage(c0);
    VMCNT(5);
    BARRIER;
    rdFrag(c2, Aa, Ba);
    mfAll(Ab, Bb);
    BARRIER;

    c0 = c2;
  }

  // ---- tail: tiles 62 (buf2, frags in Aa/Ba) and 63 (buf0) ----
  VMCNT(0);                  // tile63's 5 resident
  BARRIER;
  rdFrag(0, Ab, Bb);
  mfAll(Aa, Ba);             // tile 62
  mfAll(Ab, Bb);             // tile 63

  // ---- epilogue: bias add, f32 preds, f16 predsh, rowsum partials ----
  float rp[4][4] = {};
  #pragma unroll
  for (int m = 0; m < 4; ++m) {
    #pragma unroll
    for (int n = 0; n < 4; ++n) {
      f32x4 d = acc[m][n];
      int gc = bn0 + wn * 64 + n * 16 + (lane & 15);
      float bias = (gc < C_) ? bmv[gc] : 0.f;
      #pragma unroll
      for (int j = 0; j < 4; ++j) {
        int gr = bm0 + wm * 64 + m * 16 + (lane >> 4) * 4 + j;
        float val = d[j] + bias;
        predsh[(size_t)gr * CP + gc] = (_Float16)val;
        if (gc < C_) preds[(size_t)gr * C_ + gc] = val;
        rp[m][j] += val;
      }
    }
  }
  #pragma unroll
  for (int m = 0; m < 4; ++m) {
    #pragma unroll
    for (int j = 0; j < 4; ++j) {
      float s = rp[m][j];
      s += __shfl_xor(s, 1); s += __shfl_xor(s, 2);
      s += __shfl_xor(s, 4); s += __shfl_xor(s, 8);
      if ((lane & 15) == 0) {
        int gr = bm0 + wm * 64 + m * 16 + (lane >> 4) * 4 + j;
        atomicAdd(&rowsum[gr], s);
      }
    }
  }
}

// ---------------- gating GEMM: scores partials (r2/r5-validated) ----------------
__global__ __launch_bounds__(256) void gemm2_kernel(
    const _Float16* __restrict__ predsh, const _Float16* __restrict__ uvh,
    const float* __restrict__ wv, float* __restrict__ scores)
{
  __shared__ _Float16 sA[2][64 * 64];
  __shared__ _Float16 sB[2][128 * 64];
  const int tid  = threadIdx.x;
  const int lane = tid & 63;
  const int w    = tid >> 6;
  const int wm   = w >> 1, wn = w & 1;   // wave owns 32x64
  const int bm0  = blockIdx.x * 64;
  const int bn0  = blockIdx.y * 128;

  f32x4 acc[2][4] = {};

  const _Float16* srcA[2]; const _Float16* srcB[4];
  #pragma unroll
  for (int i = 0; i < 2; ++i) {
    int slot = i * 256 + tid;
    int row  = slot >> 3;
    int cb   = (slot & 7) << 4;
    int scb  = cb ^ ((row & 7) << 4);
    srcA[i] = predsh + (size_t)(bm0 + row) * CP + (scb >> 1);
  }
  #pragma unroll
  for (int i = 0; i < 4; ++i) {
    int slot = i * 256 + tid;
    int row  = slot >> 3;
    int cb   = (slot & 7) << 4;
    int scb  = cb ^ ((row & 7) << 4);
    srcB[i] = uvh + (size_t)(bn0 + row) * CP + (scb >> 1);
  }
  int aoff[2][2], boff[4][2];
  #pragma unroll
  for (int ks = 0; ks < 2; ++ks) {
    int kb = ks * 64 + (lane >> 4) * 16;
    #pragma unroll
    for (int mi = 0; mi < 2; ++mi) {
      int ra = wm * 32 + mi * 16 + (lane & 15);
      aoff[mi][ks] = ra * 128 + (kb ^ ((ra & 7) << 4));
    }
    #pragma unroll
    for (int ni = 0; ni < 4; ++ni) {
      int rb = wn * 64 + ni * 16 + (lane & 15);
      boff[ni][ks] = rb * 128 + (kb ^ ((rb & 7) << 4));
    }
  }

  auto stage = [&](int c) {
    #pragma unroll
    for (int i = 0; i < 2; ++i) {
      gload16(srcA[i], &sA[c][(i * 4 + w) * 512]);
      srcA[i] += 64;
    }
    #pragma unroll
    for (int i = 0; i < 4; ++i) {
      gload16(srcB[i], &sB[c][(i * 4 + w) * 512]);
      srcB[i] += 64;
    }
  };

  auto compute = [&](int c) {
    const char* bA = (const char*)&sA[c][0];
    const char* bB = (const char*)&sB[c][0];
    #pragma unroll
    for (int ks = 0; ks < 2; ++ks) {
      half8 a[2], b[4];
      #pragma unroll
      for (int mi = 0; mi < 2; ++mi) a[mi] = *(const half8*)(bA + aoff[mi][ks]);
      #pragma unroll
      for (int ni = 0; ni < 4; ++ni) b[ni] = *(const half8*)(bB + boff[ni][ks]);
      #pragma unroll
      for (int mi = 0; mi < 2; ++mi)
        #pragma unroll
        for (int ni = 0; ni < 4; ++ni)
          acc[mi][ni] = __builtin_amdgcn_mfma_f32_16x16x32_f16(a[mi], b[ni], acc[mi][ni], 0, 0, 0);
    }
  };

  const int NT = CP / 64;   // 16
  stage(0);
  #pragma unroll 1
  for (int kt = 0; kt < NT; kt += 2) {
    stage(1);
    asm volatile("s_waitcnt vmcnt(6)" ::: "memory");
    BARRIER;
    compute(0);
    BARRIER;
    if (kt + 2 < NT) {
      stage(0);
      asm volatile("s_waitcnt vmcnt(6)" ::: "memory");
    } else {
      asm volatile("s_waitcnt vmcnt(0)" ::: "memory");
    }
    BARRIER;
    compute(1);
    BARRIER;
  }

  float sp[2][4] = {};
  #pragma unroll
  for (int mi = 0; mi < 2; ++mi) {
    #pragma unroll
    for (int ni = 0; ni < 4; ++ni) {
      f32x4 d = acc[mi][ni];
      int gc = bn0 + wn * 64 + ni * 16 + (lane & 15);   // even=u col, odd=v col
      float wq = wv[gc >> 1];
      bool even = ((gc & 1) == 0);
      #pragma unroll
      for (int j = 0; j < 4; ++j) {
        float t  = d[j];
        float pr = __shfl_xor(t, 1);
        float th = 2.f / (1.f + __expf(-2.f * t)) - 1.f;
        float sg = 1.f / (1.f + __expf(-pr));
        sp[mi][j] += even ? (th * sg * wq) : 0.f;
      }
    }
  }
  #pragma unroll
  for (int mi = 0; mi < 2; ++mi) {
    #pragma unroll
    for (int j = 0; j < 4; ++j) {
      float s = sp[mi][j];
      s += __shfl_xor(s, 1); s += __shfl_xor(s, 2);
      s += __shfl_xor(s, 4); s += __shfl_xor(s, 8);
      if ((lane & 15) == 0) {
        int gr = bm0 + wm * 32 + mi * 16 + (lane >> 4) * 4 + j;
        atomicAdd(&scores[gr], s);
      }
    }
  }
}

// ---------------- final: softmax over scores, weighted rowsum ----------------
__global__ __launch_bounds__(1024) void final_kernel(
    const float* __restrict__ scores, const float* __restrict__ rowsum,
    float* __restrict__ out)
{
  __shared__ float red[16], red2[16];
  const int t = threadIdx.x;
  const int lane = t & 63, wid = t >> 6;
  float s[8];
  float m = -3.4e38f;
  #pragma unroll
  for (int i = 0; i < 8; ++i) { s[i] = scores[t + i * 1024]; m = fmaxf(m, s[i]); }
  #pragma unroll
  for (int off = 1; off < 64; off <<= 1) m = fmaxf(m, __shfl_xor(m, off));
  if (lane == 0) red[wid] = m;
  __syncthreads();
  #pragma unroll
  for (int i = 0; i < 16; ++i) m = fmaxf(m, red[i]);
  __syncthreads();

  float se = 0.f, sr = 0.f;
  #pragma unroll
  for (int i = 0; i < 8; ++i) {
    float e = __expf(s[i] - m);
    se += e;
    sr += e * rowsum[t + i * 1024];
  }
  #pragma unroll
  for (int off = 1; off < 64; off <<= 1) { se += __shfl_xor(se, off); sr += __shfl_xor(sr, off); }
  if (lane == 0) { red[wid] = se; red2[wid] = sr; }
  __syncthreads();
  if (t == 0) {
    float tse = 0.f, tsr = 0.f;
    for (int i = 0; i < 16; ++i) { tse += red[i]; tsr += red2[i]; }
    out[0] = tsr / tse;
  }
}

extern "C" void kernel_launch(void* const* d_in, const int* in_sizes, int n_in,
                              void* d_out, int out_size, void* d_ws, size_t ws_size,
                              hipStream_t stream)
{
  const float* x   = (const float*)d_in[0];
  const float* Wm  = (const float*)d_in[1];
  const float* bmv = (const float*)d_in[2];
  const float* u   = (const float*)d_in[3];
  const float* v   = (const float*)d_in[4];
  const float* wv  = (const float*)d_in[5];
  float* out = (float*)d_out;

  if (ws_size < WS_NEED) return;

  char* ws = (char*)d_ws;
  _Float16* wh     = (_Float16*)(ws + OFF_WH);
  _Float16* uvh    = (_Float16*)(ws + OFF_UVH);
  _Float16* predsh = (_Float16*)(ws + OFF_PH);
  float*    scores = (float*)(ws + OFF_SC);
  float*    rowsum = (float*)(ws + OFF_RS);

  prep_kernel<<<1288, 256, 0, stream>>>(Wm, u, v, wh, uvh, scores, rowsum);
  gemm1_kernel<<<dim3(32, 8), 512, 0, stream>>>(x, wh, bmv, out, predsh, rowsum);
  gemm2_kernel<<<dim3(128, 4), 256, 0, stream>>>(predsh, uvh, wv, scores);
  final_kernel<<<1, 1024, 0, stream>>>(scores, rowsum, out + (size_t)B_ * C_);
}

// Round 10
// 92.052 us; speedup vs baseline: 1.1196x; 1.0167x over previous
//
#include <hip/hip_runtime.h>
#include <hip/hip_fp16.h>

typedef _Float16 half8 __attribute__((ext_vector_type(8)));
typedef float f32x4 __attribute__((ext_vector_type(4)));

#define B_   8192
#define DIN  2048
#define C_   1000
#define CP   1024
#define NP2  512   // u,v interleaved rows

// ---- workspace layout (bytes) ----
static const size_t OFF_XH  = 0;                                   // xh  [8192][2048] f16
static const size_t OFF_WH  = OFF_XH  + (size_t)B_ * DIN * 2;      // wh  [1024][2048] f16 (rows>=1000 zero)
static const size_t OFF_UVH = OFF_WH  + (size_t)CP * DIN * 2;      // uvh [512][1024]  f16
static const size_t OFF_PH  = OFF_UVH + (size_t)NP2 * CP * 2;      // predsh [8192][1024] f16
static const size_t OFF_SC  = OFF_PH  + (size_t)B_ * CP * 2;       // scores [8192] f32
static const size_t OFF_RS  = OFF_SC  + (size_t)B_ * 4;            // rowsum [8192] f32
static const size_t WS_NEED = OFF_RS  + (size_t)B_ * 4;

#define FENCE asm volatile("" ::: "memory")
#define BARRIER do { FENCE; __builtin_amdgcn_s_barrier(); FENCE; } while (0)
#define VMCNT(n) asm volatile("s_waitcnt vmcnt(" #n ")" ::: "memory")
#define LGKM(n)  asm volatile("s_waitcnt lgkmcnt(" #n ")" ::: "memory")
#define SCHED0   __builtin_amdgcn_sched_barrier(0)
#define PRIO1 __builtin_amdgcn_s_setprio(1)
#define PRIO0 __builtin_amdgcn_s_setprio(0)

__device__ __forceinline__ void gload16(const void* g, void* l) {
  __builtin_amdgcn_global_load_lds(
      (const __attribute__((address_space(1))) void*)g,
      (__attribute__((address_space(3))) void*)l, 16, 0, 0);
}

// ---------------- prep: f32 -> f16 conversions + zeroing (r5-validated) ----------------
__global__ __launch_bounds__(256) void prep_kernel(
    const float* __restrict__ x, const float* __restrict__ Wm,
    const float* __restrict__ u, const float* __restrict__ v,
    _Float16* __restrict__ xh, _Float16* __restrict__ wh,
    _Float16* __restrict__ uvh, float* __restrict__ scores,
    float* __restrict__ rowsum)
{
  const long NX  = (long)B_ * DIN / 8;
  const long NW  = (long)CP * DIN / 8;
  const long NUV = (long)NP2 * CP / 8;
  const long NZ  = 2 * (long)B_ / 8;
  const long T   = NX + NW + NUV + NZ;
  for (long idx = (long)blockIdx.x * blockDim.x + threadIdx.x; idx < T;
       idx += (long)gridDim.x * blockDim.x) {
    if (idx < NX) {
      long e = idx * 8;
      float4 p0 = *(const float4*)(x + e);
      float4 p1 = *(const float4*)(x + e + 4);
      half8 h;
      h[0] = (_Float16)p0.x; h[1] = (_Float16)p0.y; h[2] = (_Float16)p0.z; h[3] = (_Float16)p0.w;
      h[4] = (_Float16)p1.x; h[5] = (_Float16)p1.y; h[6] = (_Float16)p1.z; h[7] = (_Float16)p1.w;
      *(half8*)(xh + e) = h;
    } else if (idx < NX + NW) {
      long e = (idx - NX) * 8;
      int row = (int)(e >> 11);
      half8 h;
      if (row < C_) {
        float4 p0 = *(const float4*)(Wm + e);
        float4 p1 = *(const float4*)(Wm + e + 4);
        h[0] = (_Float16)p0.x; h[1] = (_Float16)p0.y; h[2] = (_Float16)p0.z; h[3] = (_Float16)p0.w;
        h[4] = (_Float16)p1.x; h[5] = (_Float16)p1.y; h[6] = (_Float16)p1.z; h[7] = (_Float16)p1.w;
      } else {
        h = (half8)(_Float16)0.f;
      }
      *(half8*)(wh + e) = h;
    } else if (idx < NX + NW + NUV) {
      long e = (idx - NX - NW) * 8;
      int j = (int)(e >> 10);
      int k = (int)(e & 1023);
      const float* src = (j & 1) ? v : u;
      int p = j >> 1;
      half8 h;
      #pragma unroll
      for (int t = 0; t < 8; ++t) {
        int kk = k + t;
        h[t] = (kk < C_) ? (_Float16)src[(size_t)p * C_ + kk] : (_Float16)0.f;
      }
      *(half8*)(uvh + e) = h;
    } else {
      long e = (idx - NX - NW - NUV) * 8;
      float4 z = {0.f, 0.f, 0.f, 0.f};
      if (e < B_) {
        *(float4*)(scores + e) = z; *(float4*)(scores + e + 4) = z;
      } else {
        long r = e - B_;
        *(float4*)(rowsum + r) = z; *(float4*)(rowsum + r + 4) = z;
      }
    }
  }
}

// ---------------- main GEMM: preds = xh @ wh^T + bm ----------------
// Faithful m201-template port at 256x128, BK=64, 512 thr = 8 waves (4M x 2N),
// wave tile 64x64. 2 phases per K-tile; each phase:
//   {ds_read_b128 for THIS phase's MFMA (12 or 4) || 3 gload_lds stage ->
//    BARRIER -> lgkmcnt(0) -> sched_barrier(0) -> setprio(1) 16 MFMA setprio(0)
//    -> BARRIER}
// The reads issue BEFORE the barrier so their latency drains during barrier
// convergence / other waves' MFMA (the template's key ordering, absent from
// r5/r8). vmcnt(6) once per tile (FIFO: t+1's 6 retire, t+2's 6 in flight);
// lgkmcnt(8) throttle in the 12-read phase per template. 3-buffer LDS (144KB).
__global__ __launch_bounds__(512, 1) void gemm1_kernel(
    const _Float16* __restrict__ xh, const _Float16* __restrict__ wh,
    const float* __restrict__ bmv, float* __restrict__ preds,
    _Float16* __restrict__ predsh, float* __restrict__ rowsum)
{
  // A bufs (256x64 f16 = 32KB) at c*32768 ; B bufs (128x64 = 16KB) at 98304 + c*16384
  __shared__ _Float16 lds[(3 * 32768 + 3 * 16384) / 2];   // 144 KB
  char* const LB = (char*)lds;
  const int tid  = threadIdx.x;
  const int lane = tid & 63;
  const int w    = tid >> 6;       // 0..7
  const int wm   = w >> 1;         // 0..3 (M quarter: 64 rows)
  const int wn   = w & 1;          // 0..1 (N half: 64 cols)
  const int bm0  = blockIdx.x * 256;
  const int bn0  = blockIdx.y * 128;

  f32x4 acc[4][4] = {};

  // staging: pre-swizzled global source (k*64 % 8 == 0 -> swizzle k-indep),
  // linear gload_lds dest (r5/r8-validated layout).
  const int trow = tid >> 3;                       // 0..63
  const int swzc = (((tid & 7) << 4) ^ ((trow & 7) << 4)) >> 1;  // f16 units
  const _Float16* pA = xh + (size_t)(bm0 + trow) * DIN + swzc;
  const _Float16* pB = wh + (size_t)(bn0 + trow) * DIN + swzc;

  // ds_read fragment byte offsets (within one A / B buffer)
  int aoff[4][2], boff[4][2];
  #pragma unroll
  for (int m = 0; m < 4; ++m)
    #pragma unroll
    for (int ks = 0; ks < 2; ++ks) {
      int ra = wm * 64 + m * 16 + (lane & 15);
      int kb = ks * 64 + (lane >> 4) * 16;
      aoff[m][ks] = ra * 128 + (kb ^ ((ra & 7) << 4));
    }
  #pragma unroll
  for (int n = 0; n < 4; ++n)
    #pragma unroll
    for (int ks = 0; ks < 2; ++ks) {
      int rb = wn * 64 + n * 16 + (lane & 15);
      int kb = ks * 64 + (lane >> 4) * 16;
      boff[n][ks] = rb * 128 + (kb ^ ((rb & 7) << 4));
    }

  half8 A[4][2], Bf[4][2];

  auto stageH1 = [&](int c) {   // first half-tile: A k=0..2 (3 gloads)
    #pragma unroll
    for (int k = 0; k < 3; ++k)
      gload16(pA + (size_t)k * 64 * DIN, LB + c * 32768 + k * 8192 + w * 1024);
  };
  auto stageH2 = [&](int c) {   // second half: A k=3, B k=0..1 (3 gloads); advance K
    gload16(pA + (size_t)3 * 64 * DIN, LB + c * 32768 + 3 * 8192 + w * 1024);
    #pragma unroll
    for (int k = 0; k < 2; ++k)
      gload16(pB + (size_t)k * 64 * DIN, LB + 98304 + c * 16384 + k * 8192 + w * 1024);
    pA += 64; pB += 64;
  };
  auto rdA = [&](int c) {       // 8 ds_read_b128
    const char* b = LB + c * 32768;
    #pragma unroll
    for (int m = 0; m < 4; ++m)
      #pragma unroll
      for (int ks = 0; ks < 2; ++ks)
        A[m][ks] = *(const half8*)(b + aoff[m][ks]);
  };
  auto rdB01 = [&](int c) {     // 4 ds_read_b128
    const char* b = LB + 98304 + c * 16384;
    #pragma unroll
    for (int n = 0; n < 2; ++n)
      #pragma unroll
      for (int ks = 0; ks < 2; ++ks)
        Bf[n][ks] = *(const half8*)(b + boff[n][ks]);
  };
  auto rdB23 = [&](int c) {     // 4 ds_read_b128
    const char* b = LB + 98304 + c * 16384;
    #pragma unroll
    for (int n = 2; n < 4; ++n)
      #pragma unroll
      for (int ks = 0; ks < 2; ++ks)
        Bf[n][ks] = *(const half8*)(b + boff[n][ks]);
  };
  auto mfH = [&](int nlo) {     // 16 MFMA: m 0..3 x n nlo..nlo+1 x ks 0..1
    PRIO1;
    #pragma unroll
    for (int m = 0; m < 4; ++m)
      #pragma unroll
      for (int n = nlo; n < nlo + 2; ++n)
        #pragma unroll
        for (int ks = 0; ks < 2; ++ks)
          acc[m][n] = __builtin_amdgcn_mfma_f32_16x16x32_f16(A[m][ks], Bf[n][ks], acc[m][n], 0, 0, 0);
    PRIO0;
  };

  // ---- prologue: stage tile0 -> buf0, tile1 -> buf1 ----
  stageH1(0); stageH2(0);
  stageH1(1); stageH2(1);
  VMCNT(6);                  // tile0 resident (tile1's 6 in flight)
  BARRIER;

  // ---- main loop: tiles 0..29, staging tile t+2 -> buf (t+2)%3 ----
  int c0 = 0;
  #pragma unroll 1
  for (int t = 0; t < 30; ++t) {
    const int c2 = (c0 >= 1) ? c0 - 1 : 2;         // (c0+2)%3

    // phase 0: reads for THIS phase's MFMA, then barrier, then wait+compute
    rdA(c0); rdB01(c0);                            // 12 ds_read_b128
    stageH1(c2);                                   // 3 gloads
    LGKM(8);                                       // throttle (template)
    BARRIER;
    LGKM(0); SCHED0;
    mfH(0);                                        // 16 MFMA
    BARRIER;

    // phase 1
    rdB23(c0);                                     // 4 ds_read_b128
    stageH2(c2);                                   // 3 gloads
    VMCNT(6);                                      // tile t+1 resident
    BARRIER;
    LGKM(0); SCHED0;
    mfH(2);                                        // 16 MFMA
    BARRIER;

    c0 = (c0 == 2) ? 0 : c0 + 1;
  }

  // ---- tail: tile 30 (buf0) and tile 31 (buf1), no staging ----
  rdA(0); rdB01(0);
  BARRIER;
  LGKM(0); SCHED0;
  mfH(0);
  BARRIER;
  rdB23(0);
  VMCNT(0);                  // tile31's 6 resident
  BARRIER;
  LGKM(0); SCHED0;
  mfH(2);
  BARRIER;
  // tile 31: everything resident, no cross-wave hazards remain
  rdA(1); rdB01(1);
  mfH(0);
  rdB23(1);
  mfH(2);

  // ---- epilogue: bias add, f32 preds, f16 predsh, rowsum partials ----
  float rp[4][4] = {};
  #pragma unroll
  for (int m = 0; m < 4; ++m) {
    #pragma unroll
    for (int n = 0; n < 4; ++n) {
      f32x4 d = acc[m][n];
      int gc = bn0 + wn * 64 + n * 16 + (lane & 15);
      float bias = (gc < C_) ? bmv[gc] : 0.f;
      #pragma unroll
      for (int j = 0; j < 4; ++j) {
        int gr = bm0 + wm * 64 + m * 16 + (lane >> 4) * 4 + j;
        float val = d[j] + bias;
        predsh[(size_t)gr * CP + gc] = (_Float16)val;
        if (gc < C_) preds[(size_t)gr * C_ + gc] = val;
        rp[m][j] += val;
      }
    }
  }
  #pragma unroll
  for (int m = 0; m < 4; ++m) {
    #pragma unroll
    for (int j = 0; j < 4; ++j) {
      float s = rp[m][j];
      s += __shfl_xor(s, 1); s += __shfl_xor(s, 2);
      s += __shfl_xor(s, 4); s += __shfl_xor(s, 8);
      if ((lane & 15) == 0) {
        int gr = bm0 + wm * 64 + m * 16 + (lane >> 4) * 4 + j;
        atomicAdd(&rowsum[gr], s);
      }
    }
  }
}

// ---------------- gating GEMM: scores partials (r2/r5-validated) ----------------
__global__ __launch_bounds__(256) void gemm2_kernel(
    const _Float16* __restrict__ predsh, const _Float16* __restrict__ uvh,
    const float* __restrict__ wv, float* __restrict__ scores)
{
  __shared__ _Float16 sA[2][64 * 64];
  __shared__ _Float16 sB[2][128 * 64];
  const int tid  = threadIdx.x;
  const int lane = tid & 63;
  const int w    = tid >> 6;
  const int wm   = w >> 1, wn = w & 1;   // wave owns 32x64
  const int bm0  = blockIdx.x * 64;
  const int bn0  = blockIdx.y * 128;

  f32x4 acc[2][4] = {};

  const _Float16* srcA[2]; const _Float16* srcB[4];
  #pragma unroll
  for (int i = 0; i < 2; ++i) {
    int slot = i * 256 + tid;
    int row  = slot >> 3;
    int cb   = (slot & 7) << 4;
    int scb  = cb ^ ((row & 7) << 4);
    srcA[i] = predsh + (size_t)(bm0 + row) * CP + (scb >> 1);
  }
  #pragma unroll
  for (int i = 0; i < 4; ++i) {
    int slot = i * 256 + tid;
    int row  = slot >> 3;
    int cb   = (slot & 7) << 4;
    int scb  = cb ^ ((row & 7) << 4);
    srcB[i] = uvh + (size_t)(bn0 + row) * CP + (scb >> 1);
  }
  int aoff[2][2], boff[4][2];
  #pragma unroll
  for (int ks = 0; ks < 2; ++ks) {
    int kb = ks * 64 + (lane >> 4) * 16;
    #pragma unroll
    for (int mi = 0; mi < 2; ++mi) {
      int ra = wm * 32 + mi * 16 + (lane & 15);
      aoff[mi][ks] = ra * 128 + (kb ^ ((ra & 7) << 4));
    }
    #pragma unroll
    for (int ni = 0; ni < 4; ++ni) {
      int rb = wn * 64 + ni * 16 + (lane & 15);
      boff[ni][ks] = rb * 128 + (kb ^ ((rb & 7) << 4));
    }
  }

  auto stage = [&](int c) {
    #pragma unroll
    for (int i = 0; i < 2; ++i) {
      gload16(srcA[i], &sA[c][(i * 4 + w) * 512]);
      srcA[i] += 64;
    }
    #pragma unroll
    for (int i = 0; i < 4; ++i) {
      gload16(srcB[i], &sB[c][(i * 4 + w) * 512]);
      srcB[i] += 64;
    }
  };

  auto compute = [&](int c) {
    const char* bA = (const char*)&sA[c][0];
    const char* bB = (const char*)&sB[c][0];
    #pragma unroll
    for (int ks = 0; ks < 2; ++ks) {
      half8 a[2], b[4];
      #pragma unroll
      for (int mi = 0; mi < 2; ++mi) a[mi] = *(const half8*)(bA + aoff[mi][ks]);
      #pragma unroll
      for (int ni = 0; ni < 4; ++ni) b[ni] = *(const half8*)(bB + boff[ni][ks]);
      #pragma unroll
      for (int mi = 0; mi < 2; ++mi)
        #pragma unroll
        for (int ni = 0; ni < 4; ++ni)
          acc[mi][ni] = __builtin_amdgcn_mfma_f32_16x16x32_f16(a[mi], b[ni], acc[mi][ni], 0, 0, 0);
    }
  };

  const int NT = CP / 64;   // 16
  stage(0);
  #pragma unroll 1
  for (int kt = 0; kt < NT; kt += 2) {
    stage(1);
    asm volatile("s_waitcnt vmcnt(6)" ::: "memory");
    BARRIER;
    compute(0);
    BARRIER;
    if (kt + 2 < NT) {
      stage(0);
      asm volatile("s_waitcnt vmcnt(6)" ::: "memory");
    } else {
      asm volatile("s_waitcnt vmcnt(0)" ::: "memory");
    }
    BARRIER;
    compute(1);
    BARRIER;
  }

  float sp[2][4] = {};
  #pragma unroll
  for (int mi = 0; mi < 2; ++mi) {
    #pragma unroll
    for (int ni = 0; ni < 4; ++ni) {
      f32x4 d = acc[mi][ni];
      int gc = bn0 + wn * 64 + ni * 16 + (lane & 15);   // even=u col, odd=v col
      float wq = wv[gc >> 1];
      bool even = ((gc & 1) == 0);
      #pragma unroll
      for (int j = 0; j < 4; ++j) {
        float t  = d[j];
        float pr = __shfl_xor(t, 1);
        float th = 2.f / (1.f + __expf(-2.f * t)) - 1.f;
        float sg = 1.f / (1.f + __expf(-pr));
        sp[mi][j] += even ? (th * sg * wq) : 0.f;
      }
    }
  }
  #pragma unroll
  for (int mi = 0; mi < 2; ++mi) {
    #pragma unroll
    for (int j = 0; j < 4; ++j) {
      float s = sp[mi][j];
      s += __shfl_xor(s, 1); s += __shfl_xor(s, 2);
      s += __shfl_xor(s, 4); s += __shfl_xor(s, 8);
      if ((lane & 15) == 0) {
        int gr = bm0 + wm * 32 + mi * 16 + (lane >> 4) * 4 + j;
        atomicAdd(&scores[gr], s);
      }
    }
  }
}

// ---------------- final: softmax over scores, weighted rowsum ----------------
__global__ __launch_bounds__(1024) void final_kernel(
    const float* __restrict__ scores, const float* __restrict__ rowsum,
    float* __restrict__ out)
{
  __shared__ float red[16], red2[16];
  const int t = threadIdx.x;
  const int lane = t & 63, wid = t >> 6;
  float s[8];
  float m = -3.4e38f;
  #pragma unroll
  for (int i = 0; i < 8; ++i) { s[i] = scores[t + i * 1024]; m = fmaxf(m, s[i]); }
  #pragma unroll
  for (int off = 1; off < 64; off <<= 1) m = fmaxf(m, __shfl_xor(m, off));
  if (lane == 0) red[wid] = m;
  __syncthreads();
  #pragma unroll
  for (int i = 0; i < 16; ++i) m = fmaxf(m, red[i]);
  __syncthreads();

  float se = 0.f, sr = 0.f;
  #pragma unroll
  for (int i = 0; i < 8; ++i) {
    float e = __expf(s[i] - m);
    se += e;
    sr += e * rowsum[t + i * 1024];
  }
  #pragma unroll
  for (int off = 1; off < 64; off <<= 1) { se += __shfl_xor(se, off); sr += __shfl_xor(sr, off); }
  if (lane == 0) { red[wid] = se; red2[wid] = sr; }
  __syncthreads();
  if (t == 0) {
    float tse = 0.f, tsr = 0.f;
    for (int i = 0; i < 16; ++i) { tse += red[i]; tsr += red2[i]; }
    out[0] = tsr / tse;
  }
}

extern "C" void kernel_launch(void* const* d_in, const int* in_sizes, int n_in,
                              void* d_out, int out_size, void* d_ws, size_t ws_size,
                              hipStream_t stream)
{
  const float* x   = (const float*)d_in[0];
  const float* Wm  = (const float*)d_in[1];
  const float* bmv = (const float*)d_in[2];
  const float* u   = (const float*)d_in[3];
  const float* v   = (const float*)d_in[4];
  const float* wv  = (const float*)d_in[5];
  float* out = (float*)d_out;

  if (ws_size < WS_NEED) return;

  char* ws = (char*)d_ws;
  _Float16* xh     = (_Float16*)(ws + OFF_XH);
  _Float16* wh     = (_Float16*)(ws + OFF_WH);
  _Float16* uvh    = (_Float16*)(ws + OFF_UVH);
  _Float16* predsh = (_Float16*)(ws + OFF_PH);
  float*    scores = (float*)(ws + OFF_SC);
  float*    rowsum = (float*)(ws + OFF_RS);

  prep_kernel<<<2048, 256, 0, stream>>>(x, Wm, u, v, xh, wh, uvh, scores, rowsum);
  gemm1_kernel<<<dim3(32, 8), 512, 0, stream>>>(xh, wh, bmv, out, predsh, rowsum);
  gemm2_kernel<<<dim3(128, 4), 256, 0, stream>>>(predsh, uvh, wv, scores);
  final_kernel<<<1, 1024, 0, stream>>>(scores, rowsum, out + (size_t)B_ * C_);
}